// Round 7
// baseline (227.804 us; speedup 1.0000x reference)
//
#include <hip/hip_runtime.h>
#include <stdint.h>

#define PR1 73856093u
#define PR2 19349663u
#define PR3 83492791u
#define PR4 2654435761u
#define GS  32      // chunks per scan group
#define PPT 8       // points per lane per round in k_bucket_rank
#define BBITS 13    // bucket-id bits for ballot match (NB <= 8192)
#define SMALLB 16   // seps held in SGPRs when B <= SMALLB

// Branch-free uniform-divisor mod (exact for h < 2^32 via double).
__device__ __forceinline__ uint32_t fastmod(uint32_t h, uint32_t d, double inv) {
    uint32_t q = (uint32_t)((double)h * inv);
    int32_t r = (int32_t)(h - q * d);
    if (r >= (int32_t)d) r -= d;
    if (r < 0) r += d;
    return (uint32_t)r;
}

// blockIdx -> chunk swizzle: contiguous chunk runs per XCD so rank-adjacent
// output lines are RMW-merged within one XCD's L2. Any bijection is correct.
__device__ __forceinline__ int chunk_of(int bi, int C) {
    return ((C & 7) == 0) ? ((bi & 7) * (C >> 3) + (bi >> 3)) : bi;
}

// Voxel hash -> bucket id.
__device__ __forceinline__ uint32_t bucket_of(float x, float y, float z,
                                              uint32_t bid, uint32_t hop,
                                              uint32_t NBu, double invNB) {
    const uint32_t vx = (uint32_t)(int32_t)floorf(x);
    const uint32_t vy = (uint32_t)(int32_t)floorf(y);
    const uint32_t vz = (uint32_t)(int32_t)floorf(z);
    uint32_t h = vx * PR1 ^ vy * PR2 ^ vz * PR3 ^ (bid * PR4);
    h += hop;
    return fastmod(h, NBu, invNB);
}

// K1: FUSED bucket + deterministic within-chunk rank + chunk histogram.
// This is the R4 k_scatter structure (measured best: C=1024, PPT=8,
// unpacked 31KB hist, 4-wave turn loop) minus the scattered stores:
// the turn-loop atomic return IS the within-chunk arrival rank; persist
// it (u16) plus the bucket id (float, a required output). The old
// unordered-hist k1 is DELETED — one ordered-atomic pass total.
__global__ __launch_bounds__(256, 4)
void k_bucket_rank(const float* __restrict__ coords,
                   const int* __restrict__ seps, int B,
                   const int* __restrict__ hash_op_p,
                   int N, int NB, int C, int chunk, double invNB,
                   float* __restrict__ out_bucket,
                   uint16_t* __restrict__ rank_out,
                   uint16_t* __restrict__ ch) {
    extern __shared__ int hist[];          // NB running counters, init 0
    __shared__ int s_seps[1024];
    const int tid = threadIdx.x;
    for (int i = tid; i < NB; i += blockDim.x) hist[i] = 0;
    const bool smallB = (B <= SMALLB);
    int sv[SMALLB];
    if (smallB) {
        #pragma unroll
        for (int j = 0; j < SMALLB; j++) sv[j] = (j < B) ? seps[j] : 0x7fffffff;
    } else {
        const int Bc = B < 1024 ? B : 1024;
        for (int j = tid; j < Bc; j += blockDim.x) s_seps[j] = seps[j];
    }
    __syncthreads();

    const uint32_t hop = (uint32_t)hash_op_p[0];
    const uint32_t NBu = (uint32_t)NB;
    const int c = chunk_of(blockIdx.x, C);
    const int start = c * chunk;
    const int end   = min(start + chunk, N);
    const int len   = end > start ? end - start : 0;
    const int per_round = (int)blockDim.x * PPT;     // 2048
    const int rounds = (len + per_round - 1) / per_round;
    const int lane = tid & 63;
    const int wv   = tid >> 6;
    const int nw   = (int)blockDim.x >> 6;
    const unsigned long long ltmask = ((unsigned long long)1 << lane) - 1;
    int fb_bid = 0;                         // fallback running pointer (B>16)

    for (int rd = 0; rd < rounds; rd++) {
        const int wbase = start + rd * per_round + wv * (64 * PPT);
        int bs[PPT], leader[PPT], cntv[PPT], rnk[PPT];

        #pragma unroll
        for (int s = 0; s < PPT; s++) {
            const int i = wbase + s * 64 + lane;
            if (i < end) {
                const float x = coords[3 * (size_t)i + 0];
                const float y = coords[3 * (size_t)i + 1];
                const float z = coords[3 * (size_t)i + 2];
                int mybid;
                if (smallB) {
                    mybid = 0;
                    #pragma unroll
                    for (int j = 0; j < SMALLB; j++) mybid += (sv[j] <= i) ? 1 : 0;
                } else {
                    while (fb_bid < B) {
                        if (seps[fb_bid] <= i) fb_bid++; else break;
                    }
                    mybid = fb_bid;
                }
                bs[s] = (int)bucket_of(x, y, z, (uint32_t)mybid, hop, NBu, invNB);
            } else {
                bs[s] = NB;                // sentinel, fits BBITS
            }
        }

        // Ballot multi-split: mm = mask of lanes with identical bucket id.
        #pragma unroll
        for (int s = 0; s < PPT; s++) {
            const int b = bs[s];
            unsigned long long mm = ~0ull;
            #pragma unroll
            for (int k = 0; k < BBITS; k++) {
                const unsigned long long blt = __ballot(((b >> k) & 1) != 0);
                mm &= ((b >> k) & 1) ? blt : ~blt;
            }
            leader[s] = (int)__builtin_ctzll(mm);
            cntv[s]   = (int)__builtin_popcountll(mm);
            rnk[s]    = (int)__builtin_popcountll(mm & ltmask);
        }

        // Wave turn loop: arrival order = (round, wave, sub-batch, lane) =
        // ascending point index = reference arrival order. ds_add_rtn from
        // one wave issues in order -> same-bucket ranks across s correct.
        int basev[PPT];
        for (int w = 0; w < nw; w++) {
            if (wv == w) {
                #pragma unroll
                for (int s = 0; s < PPT; s++) {
                    int old = 0;
                    if (bs[s] < NB && lane == leader[s])
                        old = atomicAdd(&hist[bs[s]], cntv[s]);
                    basev[s] = __shfl(old, leader[s], 64);
                }
            }
            __syncthreads();
        }

        // Persist bucket (required output) + within-chunk rank (u16 ws).
        // Coalesced: per s, lanes write consecutive elements.
        #pragma unroll
        for (int s = 0; s < PPT; s++) {
            const int i = wbase + s * 64 + lane;
            if (i < end) {
                out_bucket[i] = (float)bs[s];
                rank_out[i] = (uint16_t)(basev[s] + rnk[s]);   // < chunk < 65536
            }
        }
    }
    // All atomics completed before the last turn-loop barrier; no further
    // hist writes -> epilogue needs no extra barrier.
    uint16_t* dst = ch + (size_t)c * NB;
    for (int i = tid; i < NB; i += blockDim.x) dst[i] = (uint16_t)hist[i];
}

// K2a: per bucket, exclusive scan within each group of GS chunks, stored
// CLAMPED at 512 (u16, in place); exact group totals -> Sg[g][b] (int).
__global__ void k_scan_group(uint16_t* __restrict__ ch, int* __restrict__ Sg,
                             int C, int NB) {
    const int b = blockIdx.x * blockDim.x + threadIdx.x;
    if (b >= NB) return;
    const int g  = blockIdx.y;
    const int c0 = g * GS;
    const int c1 = min(c0 + GS, C);
    int run = 0;
    for (int c = c0; c < c1; c++) {
        const size_t idx = (size_t)c * NB + b;
        const int v = ch[idx];
        ch[idx] = (uint16_t)(run < 512 ? run : 512);
        run += v;
    }
    Sg[(size_t)g * NB + b] = run;
}

// K2b: exclusive scan over group totals (int, exact, in place); total ->
// counts (float); fused gap-fill of unwritten slots [min(count,512),512).
__global__ void k_scan_tops(int* __restrict__ Sg, int G, int NB,
                            float* __restrict__ out_counts,
                            float* __restrict__ out_sc) {
    const int b = blockIdx.x * blockDim.x + threadIdx.x;
    if (b >= NB) return;
    int run = 0;
    for (int g = 0; g < G; g++) {
        const size_t idx = (size_t)g * NB + b;
        const int v = Sg[idx];
        Sg[idx] = run;
        run += v;
    }
    out_counts[b] = (float)run;
    const int c0 = run < 512 ? run : 512;
    float* p = out_sc + ((size_t)b * 512 + c0) * 3;
    for (int j = c0; j < 512; j++) {
        p[0] = 0.f; p[1] = 0.f; p[2] = 0.f;
        p += 3;
    }
}

// K3: pure streaming scatter. slot = min(base[c][b], 512) + rank[i]; no
// atomics, no ballots, ZERO main-loop barriers (ordering already baked into
// rank by K1). Vectorized 4-consecutive-points-per-lane: bucket float4,
// rank ushort4, coords 3x float4. Clamp semantics identical to the passing
// scheme: base>=512 or rank pushing past 512 -> slot>=512 -> dropped.
__global__ __launch_bounds__(256)
void k_scatter(const float* __restrict__ coords,
               const float* __restrict__ bucket_f,
               const uint16_t* __restrict__ rank_in,
               const uint16_t* __restrict__ ch,
               const int* __restrict__ Sg,
               int N, int NB, int C, int chunk,
               float* __restrict__ out_sc) {
    extern __shared__ uint16_t base16[];   // NB clamped bases (15.6KB)
    const int tid = threadIdx.x;
    const int c = chunk_of(blockIdx.x, C);
    const int g = c / GS;
    const uint16_t* r1 = ch + (size_t)c * NB;
    const int*      r2 = Sg + (size_t)g * NB;
    for (int i = tid; i < NB; i += blockDim.x) {
        const int v = (int)r1[i] + r2[i];
        base16[i] = (uint16_t)(v < 512 ? v : 512);
    }
    __syncthreads();

    const int start = c * chunk;            // chunk%4==0 -> start%4==0
    const int end   = min(start + chunk, N);
    for (int i0 = start + tid * 4; i0 < end; i0 += (int)blockDim.x * 4) {
        const int navail = end - i0;
        if (navail >= 4) {
            const float4* cp = (const float4*)(coords + 3 * (size_t)i0);
            const float4 a = cp[0], b4 = cp[1], c4 = cp[2];
            float xs[4], ys[4], zs[4];
            xs[0] = a.x;  ys[0] = a.y;  zs[0] = a.z;
            xs[1] = a.w;  ys[1] = b4.x; zs[1] = b4.y;
            xs[2] = b4.z; ys[2] = b4.w; zs[2] = c4.x;
            xs[3] = c4.y; ys[3] = c4.z; zs[3] = c4.w;
            const float4 bf4 = *(const float4*)(bucket_f + i0);
            const ushort4 rr = *(const ushort4*)(rank_in + i0);
            int bk[4], rk[4];
            bk[0] = (int)bf4.x; bk[1] = (int)bf4.y;
            bk[2] = (int)bf4.z; bk[3] = (int)bf4.w;
            rk[0] = rr.x; rk[1] = rr.y; rk[2] = rr.z; rk[3] = rr.w;
            #pragma unroll
            for (int p = 0; p < 4; p++) {
                const int r = (int)base16[bk[p]] + rk[p];
                if (r < 512) {
                    float* q = out_sc + ((size_t)bk[p] * 512 + r) * 3;
                    q[0] = xs[p]; q[1] = ys[p]; q[2] = zs[p];
                }
            }
        } else {
            for (int p = 0; p < navail; p++) {
                const int i = i0 + p;
                const int b = (int)bucket_f[i];
                const int r = (int)base16[b] + rank_in[i];
                if (r < 512) {
                    float* q = out_sc + ((size_t)b * 512 + r) * 3;
                    q[0] = coords[3 * (size_t)i + 0];
                    q[1] = coords[3 * (size_t)i + 1];
                    q[2] = coords[3 * (size_t)i + 2];
                }
            }
        }
    }
}

extern "C" void kernel_launch(void* const* d_in, const int* in_sizes, int n_in,
                              void* d_out, int out_size, void* d_ws, size_t ws_size,
                              hipStream_t stream) {
    const float* coords  = (const float*)d_in[0];
    const int*   seps    = (const int*)d_in[1];
    const int*   hash_op = (const int*)d_in[2];

    const int N = in_sizes[0] / 3;
    const int B = in_sizes[1];
    const int pad_to = ((N + 511) / 512) * 512;
    const int NB = pad_to / 512;

    float* out        = (float*)d_out;
    float* out_counts = out + (size_t)pad_to * 3;
    float* out_bucket = out_counts + NB;

    // Workspace: ch (u16, C x NB), Sg (int, G x NB), rank (u16, N).
    const size_t rank_bytes = (size_t)N * 2;
    int C = 1024;
    while (C > 8) {
        const int G_ = (C + GS - 1) / GS;
        if ((size_t)C * NB * 2 + (size_t)G_ * NB * 4 + rank_bytes + 64
            <= ws_size) break;
        C -= 8;
    }
    const int G = (C + GS - 1) / GS;
    int chunk = (N + C - 1) / C;
    chunk = (chunk + 3) & ~3;              // k3 vector path needs chunk%4==0
    uint16_t* ch = (uint16_t*)d_ws;
    size_t off = ((size_t)C * NB * 2 + 15) & ~(size_t)15;
    int* Sg = (int*)((char*)d_ws + off);
    off = (off + (size_t)G * NB * 4 + 15) & ~(size_t)15;
    uint16_t* rank_ws = (uint16_t*)((char*)d_ws + off);
    const size_t lds1 = (size_t)NB * sizeof(int);        // 31.25KB
    const size_t lds3 = (size_t)NB * sizeof(uint16_t);   // 15.6KB
    const double invNB = 1.0 / (double)NB;

    k_bucket_rank<<<C, 256, lds1, stream>>>(coords, seps, B, hash_op, N, NB, C,
                                            chunk, invNB, out_bucket, rank_ws, ch);
    dim3 g2a((NB + 63) / 64, G);
    k_scan_group<<<g2a, 64, 0, stream>>>(ch, Sg, C, NB);
    k_scan_tops<<<(NB + 63) / 64, 64, 0, stream>>>(Sg, G, NB, out_counts, out);
    k_scatter<<<C, 256, lds3, stream>>>(coords, out_bucket, rank_ws, ch, Sg,
                                        N, NB, C, chunk, out);
}